// Round 12
// baseline (290.761 us; speedup 1.0000x reference)
//
#include <hip/hip_runtime.h>

// Problem dims
#define B_   256
#define N_   16000
#define C_   32
#define K_   64
#define T_   124
#define NJ   125      // 128-sample half-window block sums, j = 0..124
#define HID_ 50
#define OUT_ 10
#define TB_  1024     // snnB block size
#define CURS 53       // cur/icur row stride: 53 odd -> conflict-free scalar
#define WBS  321      // sWb row stride: 321 % 32 = 1 -> 25 lanes hit 25 banks

typedef unsigned int u32;
typedef float v2f __attribute__((ext_vector_type(2)));
struct __align__(16) f2x2 { v2f lo, hi; };

// Exact single f32 ops (prevent fma contraction / reassociation).
__device__ __forceinline__ float fadd(float a, float b) { return __fadd_rn(a, b); }
__device__ __forceinline__ float fmul(float a, float b) { return __fmul_rn(a, b); }
__device__ __forceinline__ float fsub(float a, float b) { return __fsub_rn(a, b); }

// Packed f32 FMA, tap broadcast via VOP3P op_sel; taps in SGPRs.
__device__ __forceinline__ void PKFMA(v2f& y, v2f a, const f2x2& T, int k) {
    switch (k) {
    case 0:  asm("v_pk_fma_f32 %0, %1, %2, %0 op_sel:[0,0,0] op_sel_hi:[1,0,1]"
                 : "+v"(y) : "v"(a), "s"(T.lo)); break;
    case 1:  asm("v_pk_fma_f32 %0, %1, %2, %0 op_sel:[0,1,0] op_sel_hi:[1,1,1]"
                 : "+v"(y) : "v"(a), "s"(T.lo)); break;
    case 2:  asm("v_pk_fma_f32 %0, %1, %2, %0 op_sel:[0,0,0] op_sel_hi:[1,0,1]"
                 : "+v"(y) : "v"(a), "s"(T.hi)); break;
    default: asm("v_pk_fma_f32 %0, %1, %2, %0 op_sel:[0,1,0] op_sel_hi:[1,1,1]"
                 : "+v"(y) : "v"(a), "s"(T.hi)); break;
    }
}

// ---------------------------------------------------------------------------
// Kernel A: UNCHANGED r21/r8 (184 us ~= 89% of the 103 TF sustained-clock
// FMA ceiling). Do not touch.
// ---------------------------------------------------------------------------
__global__ __launch_bounds__(256, 4) void convA(const float* __restrict__ audio,
                                                const float* __restrict__ gt,
                                                float* __restrict__ Sg) {
    __shared__ __align__(16) float abI[1280];
    __shared__ __align__(16) float ybuf[4][4][272];

    const int b = blockIdx.x, g = blockIdx.y;
    const int tid = threadIdx.x, w = tid >> 6, lane = tid & 63;
    const float* arow = audio + (size_t)b * N_;

    const int origin = (g << 10) - 32;
    for (int idx = tid; idx < 1280; idx += 256) {
        int P = idx / 640, j = idx - P * 640;
        int ii = j >> 1, h = j & 1;
        int gi = origin + (P << 9) + (h << 8) + ii;
        float v = (gi >= 0 && gi < N_) ? arow[gi] : 0.0f;
        abI[P * 640 + (j ^ (((j >> 5) & 1) << 2))] = v;
    }
    __syncthreads();

    for (int G = 0; G < 2; ++G) {
        const int rowbase = __builtin_amdgcn_readfirstlane(((w << 3) + (G << 2)) << 6);
        const float* kg = gt + rowbase;

        v2f Y[2][4][4];
#pragma unroll
        for (int P = 0; P < 2; ++P)
#pragma unroll
            for (int ch = 0; ch < 4; ++ch)
#pragma unroll
                for (int d = 0; d < 4; ++d) { Y[P][ch][d].x = 0.0f; Y[P][ch][d].y = 0.0f; }

        // ---- q = 0 peel
        {
            f2x2 Tc[4];
#pragma unroll
            for (int ch = 0; ch < 4; ++ch)
                Tc[ch] = *(const f2x2*)(kg + (ch << 6));
            const int u = lane;
            const int p1 = (u << 3) ^ (((u >> 2) & 1) << 2);
#pragma unroll
            for (int P = 0; P < 2; ++P) {
                const float* abP = abI + P * 640;
                const f2x2 A0 = *(const f2x2*)(abP + p1);
                const f2x2 A1 = *(const f2x2*)(abP + (p1 ^ 4));
#pragma unroll
                for (int e = 0; e < 4; ++e) {
                    const v2f a = (e == 0) ? A0.lo : (e == 1) ? A0.hi
                                : (e == 2) ? A1.lo : A1.hi;
#pragma unroll
                    for (int ch = 0; ch < 4; ++ch)
#pragma unroll
                        for (int d = 0; d < 4; ++d) {
                            const int kb = e - 1 - d;
                            if (kb >= 0) PKFMA(Y[P][ch][d], a, Tc[ch], kb);
                        }
                }
            }
        }

        // ---- q = 1..15
#pragma unroll 1
        for (int q = 1; q < 16; ++q) {
            f2x2 Tm[4], Tc[4];
#pragma unroll
            for (int ch = 0; ch < 4; ++ch) {
                Tm[ch] = *(const f2x2*)(kg + (ch << 6) + ((q - 1) << 2));
                Tc[ch] = *(const f2x2*)(kg + (ch << 6) + (q << 2));
            }
            const int u = lane + q;
            const int p1 = (u << 3) ^ (((u >> 2) & 1) << 2);
#pragma unroll
            for (int P = 0; P < 2; ++P) {
                const float* abP = abI + P * 640;
                const f2x2 A0 = *(const f2x2*)(abP + p1);
                const f2x2 A1 = *(const f2x2*)(abP + (p1 ^ 4));
#pragma unroll
                for (int e = 0; e < 4; ++e) {
                    const v2f a = (e == 0) ? A0.lo : (e == 1) ? A0.hi
                                : (e == 2) ? A1.lo : A1.hi;
#pragma unroll
                    for (int ch = 0; ch < 4; ++ch)
#pragma unroll
                        for (int d = 0; d < 4; ++d) {
                            const int ts = e - 1 - d;
                            if (ts >= 0) PKFMA(Y[P][ch][d], a, Tc[ch], ts);
                            else         PKFMA(Y[P][ch][d], a, Tm[ch], 4 + ts);
                        }
                }
            }
        }

        // ---- q = 16 peel
        {
            f2x2 Tm[4];
#pragma unroll
            for (int ch = 0; ch < 4; ++ch)
                Tm[ch] = *(const f2x2*)(kg + (ch << 6) + 60);
            const int u = lane + 16;
            const int p1 = (u << 3) ^ (((u >> 2) & 1) << 2);
#pragma unroll
            for (int P = 0; P < 2; ++P) {
                const float* abP = abI + P * 640;
                const f2x2 A0 = *(const f2x2*)(abP + p1);
                const f2x2 A1 = *(const f2x2*)(abP + (p1 ^ 4));
#pragma unroll
                for (int e = 0; e < 4; ++e) {
                    const v2f a = (e == 0) ? A0.lo : (e == 1) ? A0.hi
                                : (e == 2) ? A1.lo : A1.hi;
#pragma unroll
                    for (int ch = 0; ch < 4; ++ch)
#pragma unroll
                        for (int d = 0; d < 4; ++d) {
                            const int ts = e - 1 - d;
                            if (ts < 0) PKFMA(Y[P][ch][d], a, Tm[ch], 4 + ts);
                        }
                }
            }
        }

        // ---- epilogue per pp
#pragma unroll
        for (int pp = 0; pp < 4; ++pp) {
            const int P = pp >> 1, h = pp & 1;
#pragma unroll
            for (int ch = 0; ch < 4; ++ch) {
                float4 z;
                z.x = fmaxf(h ? Y[P][ch][0].y : Y[P][ch][0].x, 0.0f);
                z.y = fmaxf(h ? Y[P][ch][1].y : Y[P][ch][1].x, 0.0f);
                z.z = fmaxf(h ? Y[P][ch][2].y : Y[P][ch][2].x, 0.0f);
                z.w = fmaxf(h ? Y[P][ch][3].y : Y[P][ch][3].x, 0.0f);
                *(float4*)(&ybuf[w][ch][((lane >> 5) * 136) + ((lane & 31) << 2)]) = z;
            }
            {
                const int ch2 = lane >> 4, blk = (lane >> 3) & 1, j = lane & 7;
                const float* yb = &ybuf[w][ch2][blk * 136 + j];
                float r = yb[0];
#pragma unroll
                for (int m = 1; m < 16; ++m) r = fadd(r, yb[m << 3]);
                float v = fadd(r, __shfl_xor(r, 1));
                v = fadd(v, __shfl_xor(v, 2));
                v = fadd(v, __shfl_xor(v, 4));
                const int jg = (g << 3) + (pp << 1) + blk;
                const int c = (w << 3) + (G << 2) + ch2;
                if (j == 0 && jg < NJ) Sg[((size_t)b * C_ + c) * NJ + jg] = v;
            }
        }
    }
}

// ---------------------------------------------------------------------------
// Kernel B (r23 logic at the proven 140.6 KB LDS envelope):
// patt scratch (16.4 KB, live only before cur is written) is ALIASED onto
// cur's storage (phases separated by __syncthreads; no live-range overlap).
//  - WBS 321 (==1 mod 32): bushy weight reads conflict-free, scalar staging.
//  - CURS 53 + transposed IC/AC maps (hp=tid/31): weight reads broadcast,
//    spike reads conflict-free; g-ascending fmaf order identical.
//  - mask phase: coalesced env table -> 10-bit pattern with COMPILE-TIME sf
//    (identical double-folded constants, zero runtime f64) -> integer
//    shift-assembly (exact).
// All per-output float accumulation orders unchanged: bit-exact.
// ---------------------------------------------------------------------------
__global__ __launch_bounds__(TB_, 1) void snnB(const float* __restrict__ Sg,
                                               const float* __restrict__ Wb,
                                               const float* __restrict__ Wic,
                                               const float* __restrict__ Wac,
                                               float* __restrict__ out) {
    __shared__ float sWb[HID_ * WBS];                 // 64,200 B
    __shared__ float sWic[HID_ * CURS];               // 10,600 B
    __shared__ float sWac[OUT_ * CURS];               //  2,120 B
    __shared__ u32   mask[1280];                      //  5,120 B
    __shared__ __align__(16) float cur[T_ * CURS];    // 26,288 B (patt aliased)
    __shared__ __align__(16) float icur[T_ * CURS];   // 26,288 B
    __shared__ float acur[T_ * 12];                   //  5,952 B  (140,568 B)

    const int b = blockIdx.x, tid = threadIdx.x;
    u32* patt = (u32*)cur;   // C_*128 u32 = 16,384 B <= sizeof(cur); dead
                             // before the first cur write (barrier-separated)

    for (int i = tid; i < HID_ * 320; i += TB_) {
        int r = i / 320;
        sWb[r * WBS + (i - r * 320)] = Wb[i];
    }
    for (int i = tid; i < HID_ * HID_; i += TB_) {
        int r = i / 50;
        sWic[r * CURS + (i - r * 50)] = Wic[i];
    }
    for (int i = tid; i < OUT_ * HID_; i += TB_) {
        int r = i / 50;
        sWac[r * CURS + (i - r * 50)] = Wac[i];
    }

    // ---- env + 10-bit spike pattern per (c,t). sf folds to compile-time
    // constants (double-derived, identical values to the reference).
    const float* Sb = Sg + (size_t)b * C_ * NJ;
    for (int idx = tid; idx < C_ * T_; idx += TB_) {
        int c = idx / T_, t = idx - c * T_;              // t-minor: coalesced Sb
        float env = fmul(fadd(Sb[c * NJ + t], Sb[c * NJ + t + 1]), 0.00390625f);
        u32 p = 0;
#pragma unroll
        for (int s = 0; s < 10; ++s) {
            const float sf = (s == 9) ? 1.5f : (float)(0.5 + (double)s * (1.0 / 9.0));
            if (fsub(fmul(env, sf), 0.5f) > 0.0f) p |= (1u << s);
        }
        patt[c * 128 + t] = p;
    }
    __syncthreads();

    // ---- assemble 32-bit mask words from patterns (pure integer, exact)
    for (int idx = tid; idx < 1280; idx += TB_) {
        if (idx >= T_ * 10) { mask[idx] = 0; continue; }
        int t = idx / 10, wd = idx - t * 10;
        const int bit0 = wd << 5;
        const int c0 = bit0 / 10;
        u32 m = 0;
#pragma unroll
        for (int cc = 0; cc < 5; ++cc) {
            int c = c0 + cc;
            int sh = c * 10 - bit0;
            if (c < C_ && sh < 32) {
                u32 p = patt[c * 128 + t];
                m |= (sh >= 0) ? (p << sh) : (p >> (-sh));
            }
        }
        mask[idx] = m;
    }
    __syncthreads();      // patt dead from here; cur storage reused below

    // ---- Bushy currents: t-quad (t0+{0,31,62,93}) x h-pair (hp, hp+25).
    // wr reads: stride-321 -> 25 lanes hit 25 distinct banks (conflict-free).
    if (tid < 31 * 25) {
        const int t0 = tid / 25, hp = tid - t0 * 25;
        const float* wr0 = sWb + hp * WBS;
        const float* wr1 = sWb + (hp + 25) * WBS;
        const u32* mrow = mask + t0 * 10;
        v2f a0 = {0.0f, 0.0f}, a1 = {0.0f, 0.0f};   // x = h=hp, y = h=hp+25
        v2f a2 = {0.0f, 0.0f}, a3 = {0.0f, 0.0f};
        u32 wbuf0[10], wbuf1[10], wbuf2[10], wbuf3[10];
#pragma unroll
        for (int wi = 0; wi < 10; ++wi) {
            wbuf0[wi] = mrow[wi];
            wbuf1[wi] = mrow[310 + wi];
            wbuf2[wi] = mrow[620 + wi];
            wbuf3[wi] = mrow[930 + wi];
        }
#pragma unroll 1
        for (int wi = 0; wi < 10; ++wi) {
            const u32 w0 = wbuf0[wi], w1 = wbuf1[wi];
            const u32 w2 = wbuf2[wi], w3 = wbuf3[wi];
#pragma unroll
            for (int b2 = 0; b2 < 32; ++b2) {
                const int i = (wi << 5) + b2;
                const int iw0 = __float_as_int(wr0[i]);
                const int iw1 = __float_as_int(wr1[i]);
                const int s0 = __builtin_amdgcn_sbfe((int)w0, b2, 1);
                const int s1 = __builtin_amdgcn_sbfe((int)w1, b2, 1);
                const int s2 = __builtin_amdgcn_sbfe((int)w2, b2, 1);
                const int s3 = __builtin_amdgcn_sbfe((int)w3, b2, 1);
                v2f p0, p1, p2, p3;
                p0.x = __int_as_float(iw0 & s0);  p0.y = __int_as_float(iw1 & s0);
                p1.x = __int_as_float(iw0 & s1);  p1.y = __int_as_float(iw1 & s1);
                p2.x = __int_as_float(iw0 & s2);  p2.y = __int_as_float(iw1 & s2);
                p3.x = __int_as_float(iw0 & s3);  p3.y = __int_as_float(iw1 & s3);
                a0 = a0 + p0;   // v_pk_add_f32: each half IEEE fadd
                a1 = a1 + p1;
                a2 = a2 + p2;
                a3 = a3 + p3;
            }
        }
        cur[(t0     ) * CURS + hp] = a0.x;  cur[(t0     ) * CURS + hp + 25] = a0.y;
        cur[(t0 + 31) * CURS + hp] = a1.x;  cur[(t0 + 31) * CURS + hp + 25] = a1.y;
        cur[(t0 + 62) * CURS + hp] = a2.x;  cur[(t0 + 62) * CURS + hp + 25] = a2.y;
        cur[(t0 + 93) * CURS + hp] = a3.x;  cur[(t0 + 93) * CURS + hp + 25] = a3.y;
    }
    __syncthreads();

    // ---- Bushy membrane chains: batch-8
    if (tid < HID_) {
        float mem = 0.0f;
        for (int t0 = 0; t0 < 120; t0 += 8) {
            float c0[8];
#pragma unroll
            for (int k = 0; k < 8; ++k) c0[k] = cur[(t0 + k) * CURS + tid];
#pragma unroll
            for (int k = 0; k < 8; ++k) {
                float m = fadd(fmul(0.95f, mem), c0[k]);
                float sp = (fsub(m, 1.0f) > 0.0f) ? 1.0f : 0.0f;
                mem = fsub(m, sp);
                cur[(t0 + k) * CURS + tid] = sp;
            }
        }
        for (int t = 120; t < T_; ++t) {
            float m = fadd(fmul(0.95f, mem), cur[t * CURS + tid]);
            float sp = (fsub(m, 1.0f) > 0.0f) ? 1.0f : 0.0f;
            mem = fsub(m, sp);
            cur[t * CURS + tid] = sp;
        }
    }
    __syncthreads();

    // ---- IC currents: transposed map (hp = tid/31, tl = tid%31):
    // weight reads wave-broadcast, spike reads stride-53 conflict-free.
    if (tid < 31 * 25) {
        const int hp = tid / 31, tl = tid - hp * 31;
        const float* w0 = sWic + hp * CURS;
        const float* w1 = sWic + (hp + 25) * CURS;
        const float* sb0 = cur + (tl     ) * CURS;
        const float* sb1 = cur + (tl + 31) * CURS;
        const float* sb2 = cur + (tl + 62) * CURS;
        const float* sb3 = cur + (tl + 93) * CURS;
        float A00 = 0.0f, A01 = 0.0f, A10 = 0.0f, A11 = 0.0f;
        float A20 = 0.0f, A21 = 0.0f, A30 = 0.0f, A31 = 0.0f;
#pragma unroll 10
        for (int g = 0; g < HID_; ++g) {
            const float wa = w0[g], wb = w1[g];
            const float s0 = sb0[g], s1 = sb1[g], s2 = sb2[g], s3 = sb3[g];
            A00 = fmaf(s0, wa, A00);  A01 = fmaf(s0, wb, A01);
            A10 = fmaf(s1, wa, A10);  A11 = fmaf(s1, wb, A11);
            A20 = fmaf(s2, wa, A20);  A21 = fmaf(s2, wb, A21);
            A30 = fmaf(s3, wa, A30);  A31 = fmaf(s3, wb, A31);
        }
        icur[(tl     ) * CURS + hp] = A00;  icur[(tl     ) * CURS + hp + 25] = A01;
        icur[(tl + 31) * CURS + hp] = A10;  icur[(tl + 31) * CURS + hp + 25] = A11;
        icur[(tl + 62) * CURS + hp] = A20;  icur[(tl + 62) * CURS + hp + 25] = A21;
        icur[(tl + 93) * CURS + hp] = A30;  icur[(tl + 93) * CURS + hp + 25] = A31;
    }
    __syncthreads();

    // ---- IC membrane chains: batch-8
    if (tid < HID_) {
        float mem = 0.0f;
        for (int t0 = 0; t0 < 120; t0 += 8) {
            float c0[8];
#pragma unroll
            for (int k = 0; k < 8; ++k) c0[k] = icur[(t0 + k) * CURS + tid];
#pragma unroll
            for (int k = 0; k < 8; ++k) {
                float m = fadd(fmul(0.95f, mem), c0[k]);
                float sp = (fsub(m, 1.0f) > 0.0f) ? 1.0f : 0.0f;
                mem = fsub(m, sp);
                icur[(t0 + k) * CURS + tid] = sp;
            }
        }
        for (int t = 120; t < T_; ++t) {
            float m = fadd(fmul(0.95f, mem), icur[t * CURS + tid]);
            float sp = (fsub(m, 1.0f) > 0.0f) ? 1.0f : 0.0f;
            mem = fsub(m, sp);
            icur[t * CURS + tid] = sp;
        }
    }
    __syncthreads();

    // ---- AC currents: transposed map (op = tid/31)
    if (tid < 31 * 5) {
        const int op = tid / 31, tl = tid - op * 31;
        const float* w0 = sWac + op * CURS;
        const float* w1 = sWac + (op + 5) * CURS;
        const float* sb0 = icur + (tl     ) * CURS;
        const float* sb1 = icur + (tl + 31) * CURS;
        const float* sb2 = icur + (tl + 62) * CURS;
        const float* sb3 = icur + (tl + 93) * CURS;
        float A00 = 0.0f, A01 = 0.0f, A10 = 0.0f, A11 = 0.0f;
        float A20 = 0.0f, A21 = 0.0f, A30 = 0.0f, A31 = 0.0f;
#pragma unroll 10
        for (int g = 0; g < HID_; ++g) {
            const float wa = w0[g], wb = w1[g];
            const float s0 = sb0[g], s1 = sb1[g], s2 = sb2[g], s3 = sb3[g];
            A00 = fmaf(s0, wa, A00);  A01 = fmaf(s0, wb, A01);
            A10 = fmaf(s1, wa, A10);  A11 = fmaf(s1, wb, A11);
            A20 = fmaf(s2, wa, A20);  A21 = fmaf(s2, wb, A21);
            A30 = fmaf(s3, wa, A30);  A31 = fmaf(s3, wb, A31);
        }
        acur[(tl     ) * 12 + op] = A00;  acur[(tl     ) * 12 + op + 5] = A01;
        acur[(tl + 31) * 12 + op] = A10;  acur[(tl + 31) * 12 + op + 5] = A11;
        acur[(tl + 62) * 12 + op] = A20;  acur[(tl + 62) * 12 + op + 5] = A21;
        acur[(tl + 93) * 12 + op] = A30;  acur[(tl + 93) * 12 + op + 5] = A31;
    }
    __syncthreads();

    // ---- AC membrane chains + output stores: batch-8
    if (tid < OUT_) {
        float mem = 0.0f;
        for (int t0 = 0; t0 < 120; t0 += 8) {
            float c0[8];
#pragma unroll
            for (int k = 0; k < 8; ++k) c0[k] = acur[(t0 + k) * 12 + tid];
#pragma unroll
            for (int k = 0; k < 8; ++k) {
                float m = fadd(fmul(0.95f, mem), c0[k]);
                float sp = (fsub(m, 1.0f) > 0.0f) ? 1.0f : 0.0f;
                float mo = fsub(m, sp);
                mem = mo;
                size_t base = ((size_t)b * T_ + (t0 + k)) * OUT_ + tid;
                out[base] = sp;
                out[(size_t)(B_ * T_ * OUT_) + base] = mo;
            }
        }
        for (int t = 120; t < T_; ++t) {
            float m = fadd(fmul(0.95f, mem), acur[t * 12 + tid]);
            float sp = (fsub(m, 1.0f) > 0.0f) ? 1.0f : 0.0f;
            float mo = fsub(m, sp);
            mem = mo;
            size_t base = ((size_t)b * T_ + t) * OUT_ + tid;
            out[base] = sp;
            out[(size_t)(B_ * T_ * OUT_) + base] = mo;
        }
    }
}

// ---------------------------------------------------------------------------
extern "C" void kernel_launch(void* const* d_in, const int* in_sizes, int n_in,
                              void* d_out, int out_size, void* d_ws, size_t ws_size,
                              hipStream_t stream) {
    (void)in_sizes; (void)n_in; (void)out_size; (void)ws_size;
    const float* audio = (const float*)d_in[0];
    const float* gt    = (const float*)d_in[1];
    const float* Wb    = (const float*)d_in[2];
    const float* Wic   = (const float*)d_in[3];
    const float* Wac   = (const float*)d_in[4];

    float* Sg = (float*)d_ws;   // needs 256*32*125*4 = 4,096,000 B of ws

    convA<<<dim3(B_, 16), dim3(256), 0, stream>>>(audio, gt, Sg);
    snnB<<<dim3(B_), dim3(TB_), 0, stream>>>(Sg, Wb, Wic, Wac, (float*)d_out);
}